// Round 1
// baseline (12801.831 us; speedup 1.0000x reference)
//
#include <hip/hip_runtime.h>

#define BATCH 512
#define TT    256
#define II    256
#define HH    512

typedef float f32x4  __attribute__((ext_vector_type(4)));
typedef unsigned short u16x8 __attribute__((ext_vector_type(8)));
typedef short bfrag  __attribute__((ext_vector_type(8)));   // 8 bf16 = 4 VGPRs (MFMA A/B operand)

__device__ inline unsigned short f2bf(float f) {
    unsigned u = __float_as_uint(f);
    return (unsigned short)((u + 0x7fffu + ((u >> 16) & 1u)) >> 16);   // RNE
}
__device__ inline float bf2f(unsigned short h) { return __uint_as_float(((unsigned)h) << 16); }

__device__ inline bfrag cvt8(const float* p) {   // 8 fp32 -> bf16 frag
    float4 a = *(const float4*)p;
    float4 b = *(const float4*)(p + 4);
    u16x8 u;
    u[0]=f2bf(a.x); u[1]=f2bf(a.y); u[2]=f2bf(a.z); u[3]=f2bf(a.w);
    u[4]=f2bf(b.x); u[5]=f2bf(b.y); u[6]=f2bf(b.z); u[7]=f2bf(b.w);
    return __builtin_bit_cast(bfrag, u);
}
__device__ inline bfrag ld8(const unsigned short* p) {
    return __builtin_bit_cast(bfrag, *(const u16x8*)p);
}
__device__ inline float sigm(float x) { return 1.f / (1.f + __expf(-x)); }
__device__ inline float tanh_(float x) {       // overflow-safe tanh via exp
    float ax = fabsf(x);
    float e  = __expf(-2.f * ax);
    float t  = (1.f - e) / (1.f + e);
    return copysignf(t, x);
}

// ---------------- x -> bf16 pre-cast (parallel, memory-bound) ----------------
__global__ __launch_bounds__(256) void cast_x_kernel(const float* __restrict__ x,
                                                     unsigned short* __restrict__ xb) {
    long i = ((long)blockIdx.x * 256 + threadIdx.x) * 8;
    float4 a = *(const float4*)(x + i);
    float4 b = *(const float4*)(x + i + 4);
    u16x8 u;
    u[0]=f2bf(a.x); u[1]=f2bf(a.y); u[2]=f2bf(a.z); u[3]=f2bf(a.w);
    u[4]=f2bf(b.x); u[5]=f2bf(b.y); u[6]=f2bf(b.z); u[7]=f2bf(b.w);
    *(u16x8*)(xb + i) = u;
}

// ---------------- persistent LSTM recurrence ----------------
// grid 256 blocks x 256 thr. group = batch slice of 32 rows (16 groups);
// 16 WGs/group split the 2048 gate cols (32 h-cols each). XCD-local groups via %8 swizzle.
// Wave (0..3) owns 8 h-cols x 4 gates (2 n-tiles) x 32 rows (2 m-tiles) = 4 C-tiles.
__global__ __launch_bounds__(256, 1) void lstm_persist(
    const float* __restrict__ Wih, const float* __restrict__ Whh,
    const float* __restrict__ bih, const float* __restrict__ bhh,
    const unsigned short* __restrict__ xb,   // (B,T,I) bf16
    unsigned short* __restrict__ hs,         // (B,T,H) bf16  (ws)
    unsigned int* __restrict__ syncw)        // 16 groups * 64 uints, zeroed
{
    const int tid  = threadIdx.x;
    const int bx   = blockIdx.x;
    const int grp  = ((bx & 7) << 1) | ((bx >> 3) & 1);  // 2 groups per XCD (round-robin heuristic)
    const int wg   = bx >> 4;                            // 0..15: gate-col slice
    const int w    = tid >> 6;                           // wave 0..3
    const int lane = tid & 63;
    const int quad = lane >> 4;
    const int ct   = lane & 15;
    const bool lo  = (ct < 8);
    const int rb0  = grp * 32;                           // batch rows [rb0, rb0+32)
    const int hw0  = wg * 32 + w * 8;                    // this wave's 8 h-cols
    const int hcol = hw0 + (ct & 7);

    __shared__ unsigned short sh[32 * 520];              // h(t-1) tile, rows padded 512->520

    // W rows for this lane's two n-tiles: nt0 -> gates {i,f}, nt1 -> gates {g,o}
    int wrow[2];
    wrow[0] = ((ct >> 3) + 0) * HH + hcol;
    wrow[1] = ((ct >> 3) + 2) * HH + hcol;

    // ---- weights resident in registers (constant across all 256 steps) ----
    bfrag wih_f[8][2], whh_f[16][2];
#pragma unroll
    for (int kk = 0; kk < 8; ++kk)
#pragma unroll
        for (int nt = 0; nt < 2; ++nt)
            wih_f[kk][nt] = cvt8(Wih + (long)wrow[nt] * II + kk * 32 + quad * 8);
#pragma unroll
    for (int kk = 0; kk < 16; ++kk)
#pragma unroll
        for (int nt = 0; nt < 2; ++nt)
            whh_f[kk][nt] = cvt8(Whh + (long)wrow[nt] * HH + kk * 32 + quad * 8);

    float bb[2];
    bb[0] = bih[wrow[0]] + bhh[wrow[0]];
    bb[1] = bih[wrow[1]] + bhh[wrow[1]];

    float cst[2][4];                                    // fp32 cell state, never rounded
#pragma unroll
    for (int mt = 0; mt < 2; ++mt)
#pragma unroll
        for (int r = 0; r < 4; ++r) cst[mt][r] = 0.f;

    unsigned int* cnt = syncw + grp * 64;
    unsigned int* gen = cnt + 16;

    for (int t = 0; t < TT; ++t) {
        f32x4 acc[2][2];
#pragma unroll
        for (int mt = 0; mt < 2; ++mt)
#pragma unroll
            for (int nt = 0; nt < 2; ++nt)
                acc[mt][nt] = (f32x4){bb[nt], bb[nt], bb[nt], bb[nt]};

        // ---- x part (independent of barrier; hides arrive->release latency) ----
#pragma unroll
        for (int kk = 0; kk < 8; ++kk) {
#pragma unroll
            for (int mt = 0; mt < 2; ++mt) {
                bfrag a = ld8(xb + ((long)(rb0 + mt * 16 + ct) * TT + t) * II + kk * 32 + quad * 8);
#pragma unroll
                for (int nt = 0; nt < 2; ++nt)
                    acc[mt][nt] = __builtin_amdgcn_mfma_f32_16x16x32_bf16(a, wih_f[kk][nt], acc[mt][nt], 0, 0, 0);
            }
        }

        if (t > 0) {
            // ---- wait for h(t-1) from the other 15 WGs of this group ----
            if (tid == 0) {
                while (__hip_atomic_load(gen, __ATOMIC_ACQUIRE, __HIP_MEMORY_SCOPE_AGENT) < (unsigned)t)
                    __builtin_amdgcn_s_sleep(1);
            }
            __syncthreads();
            __threadfence();   // acquire side: invalidate stale cached h

            // ---- stage h(t-1) 32x512 bf16 -> LDS (padded rows) ----
#pragma unroll
            for (int j = 0; j < 8; ++j) {
                int cid = j * 256 + tid;               // 2048 x 16B chunks
                int row = cid >> 6, c16 = cid & 63;
                u16x8 v = *(const u16x8*)(hs + ((long)(rb0 + row) * TT + (t - 1)) * HH + c16 * 8);
                *(u16x8*)(sh + row * 520 + c16 * 8) = v;
            }
            __syncthreads();

            // ---- h part: A from LDS, B from registers ----
#pragma unroll
            for (int kk = 0; kk < 16; ++kk) {
                bfrag a[2];
#pragma unroll
                for (int mt = 0; mt < 2; ++mt)
                    a[mt] = ld8(sh + (mt * 16 + ct) * 520 + kk * 32 + quad * 8);
#pragma unroll
                for (int mt = 0; mt < 2; ++mt)
#pragma unroll
                    for (int nt = 0; nt < 2; ++nt)
                        acc[mt][nt] = __builtin_amdgcn_mfma_f32_16x16x32_bf16(a[mt], whh_f[kk][nt], acc[mt][nt], 0, 0, 0);
            }
        }

        // ---- elementwise epilogue; lanes l and l^8 hold complementary gate pairs ----
#pragma unroll
        for (int mt = 0; mt < 2; ++mt) {
#pragma unroll
            for (int r = 0; r < 4; ++r) {
                float a0 = acc[mt][0][r], a1 = acc[mt][1][r];
                float b0 = __shfl_xor(a0, 8, 64);
                float b1 = __shfl_xor(a1, 8, 64);
                float iv = lo ? a0 : b0;
                float fv = lo ? b0 : a0;
                float gv = lo ? a1 : b1;
                float ov = lo ? b1 : a1;
                iv = sigm(iv); fv = sigm(fv); gv = tanh_(gv); ov = sigm(ov);
                float c = fv * cst[mt][r] + iv * gv;
                cst[mt][r] = c;
                float h = ov * tanh_(c);
                if (lo) {
                    int b = rb0 + mt * 16 + quad * 4 + r;
                    hs[((long)b * TT + t) * HH + hcol] = f2bf(h);
                }
            }
        }

        // ---- arrive (release h(t)); spin happens at top of next iteration ----
        __threadfence();
        __syncthreads();
        if (tid == 0) {
            unsigned old = __hip_atomic_fetch_add(cnt, 1u, __ATOMIC_ACQ_REL, __HIP_MEMORY_SCOPE_AGENT);
            if (old == 15u) {
                __hip_atomic_store(cnt, 0u, __ATOMIC_RELAXED, __HIP_MEMORY_SCOPE_AGENT);
                __hip_atomic_store(gen, (unsigned)(t + 1), __ATOMIC_RELEASE, __HIP_MEMORY_SCOPE_AGENT);
            }
        }
    }
}

// ---------------- attention pooling ----------------
__global__ __launch_bounds__(256) void attn_kernel(const unsigned short* __restrict__ hs,
                                                   float* __restrict__ out) {
    int b = blockIdx.x, tid = threadIdx.x;
    int w = tid >> 6, lane = tid & 63;
    __shared__ float sc[TT];
    __shared__ float hl[HH];
    for (int c = tid; c < HH; c += 256)
        hl[c] = bf2f(hs[((long)b * TT + (TT - 1)) * HH + c]);
    __syncthreads();
    float hr[8];
#pragma unroll
    for (int j = 0; j < 8; ++j) hr[j] = hl[lane * 8 + j];
    for (int t = w; t < TT; t += 4) {                 // scores, wave-parallel over t
        u16x8 hv = *(const u16x8*)(hs + ((long)b * TT + t) * HH + lane * 8);
        float p = 0.f;
#pragma unroll
        for (int j = 0; j < 8; ++j) p += bf2f(hv[j]) * hr[j];
#pragma unroll
        for (int off = 32; off; off >>= 1) p += __shfl_xor(p, off, 64);
        if (lane == 0) sc[t] = p;
    }
    __syncthreads();
    float denom = 0.f;
    for (int t = 0; t < TT; ++t) denom += sc[t];
    float c0 = 0.f, c1 = 0.f;
    int col = tid * 2;
    for (int t = 0; t < TT; ++t) {
        float s = sc[t];
        unsigned v = *(const unsigned*)(hs + ((long)b * TT + t) * HH + col);
        c0 += s * __uint_as_float((v & 0xffffu) << 16);
        c1 += s * __uint_as_float(v & 0xffff0000u);
    }
    out[(long)b * HH + col]     = c0 / denom;
    out[(long)b * HH + col + 1] = c1 / denom;
}

extern "C" void kernel_launch(void* const* d_in, const int* in_sizes, int n_in,
                              void* d_out, int out_size, void* d_ws, size_t ws_size,
                              hipStream_t stream) {
    const float* x   = (const float*)d_in[0];
    const float* Wih = (const float*)d_in[1];
    const float* Whh = (const float*)d_in[2];
    const float* bih = (const float*)d_in[3];
    const float* bhh = (const float*)d_in[4];
    float* out = (float*)d_out;

    char* ws = (char*)d_ws;
    unsigned int*   syncw = (unsigned int*)ws;                          // 4 KB
    unsigned short* hs    = (unsigned short*)(ws + 4096);               // 134.2 MB
    unsigned short* xb    = (unsigned short*)(ws + 4096 + (size_t)BATCH * TT * HH * 2); // 67.1 MB

    hipMemsetAsync(syncw, 0, 4096, stream);
    cast_x_kernel<<<(BATCH * TT * II) / (256 * 8), 256, 0, stream>>>(x, xb);
    lstm_persist<<<256, 256, 0, stream>>>(Wih, Whh, bih, bhh, xb, hs, syncw);
    attn_kernel<<<BATCH, 256, 0, stream>>>(hs, out);
}

// Round 3
// 2325.521 us; speedup vs baseline: 5.5049x; 5.5049x over previous
//
#include <hip/hip_runtime.h>

#define BATCH 512
#define TT    256
#define II    256
#define HH    512

typedef float f32x4  __attribute__((ext_vector_type(4)));
typedef unsigned short u16x8 __attribute__((ext_vector_type(8)));
typedef short bfrag  __attribute__((ext_vector_type(8)));   // 8 bf16 = 4 VGPRs (MFMA A/B operand)

__device__ inline unsigned short f2bf(float f) {
    unsigned u = __float_as_uint(f);
    return (unsigned short)((u + 0x7fffu + ((u >> 16) & 1u)) >> 16);   // RNE
}
__device__ inline float bf2f(unsigned short h) { return __uint_as_float(((unsigned)h) << 16); }

__device__ inline bfrag cvt8(const float* p) {   // 8 fp32 -> bf16 frag
    float4 a = *(const float4*)p;
    float4 b = *(const float4*)(p + 4);
    u16x8 u;
    u[0]=f2bf(a.x); u[1]=f2bf(a.y); u[2]=f2bf(a.z); u[3]=f2bf(a.w);
    u[4]=f2bf(b.x); u[5]=f2bf(b.y); u[6]=f2bf(b.z); u[7]=f2bf(b.w);
    return __builtin_bit_cast(bfrag, u);
}
__device__ inline bfrag ld8(const unsigned short* p) {
    return __builtin_bit_cast(bfrag, *(const u16x8*)p);
}
__device__ inline float sigm(float x) { return 1.f / (1.f + __expf(-x)); }
__device__ inline float tanh_(float x) {       // overflow-safe tanh via exp
    float ax = fabsf(x);
    float e  = __expf(-2.f * ax);
    float t  = (1.f - e) / (1.f + e);
    return copysignf(t, x);
}

// ---------------- x -> bf16 pre-cast (parallel, memory-bound) ----------------
__global__ __launch_bounds__(256) void cast_x_kernel(const float* __restrict__ x,
                                                     unsigned short* __restrict__ xb) {
    long i = ((long)blockIdx.x * 256 + threadIdx.x) * 8;
    float4 a = *(const float4*)(x + i);
    float4 b = *(const float4*)(x + i + 4);
    u16x8 u;
    u[0]=f2bf(a.x); u[1]=f2bf(a.y); u[2]=f2bf(a.z); u[3]=f2bf(a.w);
    u[4]=f2bf(b.x); u[5]=f2bf(b.y); u[6]=f2bf(b.z); u[7]=f2bf(b.w);
    *(u16x8*)(xb + i) = u;
}

// ---------------- persistent LSTM recurrence ----------------
// grid 256 blocks x 256 thr. group = batch slice of 32 rows (16 groups);
// 16 WGs/group split the 2048 gate cols (32 h-cols each).
// ALL cross-WG traffic (h tiles + flags) goes through IF$ via sc0/sc1 ops —
// no L2 dirty lines, so no buffer_wbl2/buffer_inv fences anywhere (R1's 49us/step killer).
__global__ __launch_bounds__(256, 1) void lstm_persist(
    const float* __restrict__ Wih, const float* __restrict__ Whh,
    const float* __restrict__ bih, const float* __restrict__ bhh,
    const unsigned short* __restrict__ xb,   // (B,T,I) bf16
    unsigned short* __restrict__ hs,         // (B,T,H) bf16  (ws)
    unsigned int* __restrict__ flags)        // [16 grp][256 t][16 wg], zeroed per launch
{
    const int tid  = threadIdx.x;
    const int bx   = blockIdx.x;
    const int grp  = bx >> 4;                            // batch slice
    const int wg   = bx & 15;                            // gate-col slice
    const int w    = tid >> 6;                           // wave 0..3
    const int lane = tid & 63;
    const int quad = lane >> 4;
    const int ct   = lane & 15;
    const bool lo  = (ct < 8);
    const int rb0  = grp * 32;                           // batch rows [rb0, rb0+32)
    const int hw0  = wg * 32 + w * 8;                    // this wave's 8 h-cols
    const int hcol = hw0 + (ct & 7);

    __shared__ unsigned short sh[32 * 520];              // h(t-1) tile, rows padded 512->520

    // W rows for this lane's two n-tiles: nt0 -> gates {i,f}, nt1 -> gates {g,o}
    int wrow[2];
    wrow[0] = ((ct >> 3) + 0) * HH + hcol;
    wrow[1] = ((ct >> 3) + 2) * HH + hcol;

    // ---- weights resident in registers (constant across all 256 steps) ----
    bfrag wih_f[8][2], whh_f[16][2];
#pragma unroll
    for (int kk = 0; kk < 8; ++kk)
#pragma unroll
        for (int nt = 0; nt < 2; ++nt)
            wih_f[kk][nt] = cvt8(Wih + (long)wrow[nt] * II + kk * 32 + quad * 8);
#pragma unroll
    for (int kk = 0; kk < 16; ++kk)
#pragma unroll
        for (int nt = 0; nt < 2; ++nt)
            whh_f[kk][nt] = cvt8(Whh + (long)wrow[nt] * HH + kk * 32 + quad * 8);

    float bb[2];
    bb[0] = bih[wrow[0]] + bhh[wrow[0]];
    bb[1] = bih[wrow[1]] + bhh[wrow[1]];

    float cst[2][4];                                    // fp32 cell state, never rounded
#pragma unroll
    for (int mt = 0; mt < 2; ++mt)
#pragma unroll
        for (int r = 0; r < 4; ++r) cst[mt][r] = 0.f;

    for (int t = 0; t < TT; ++t) {
        f32x4 acc[2][2];
#pragma unroll
        for (int mt = 0; mt < 2; ++mt)
#pragma unroll
            for (int nt = 0; nt < 2; ++nt)
                acc[mt][nt] = (f32x4){bb[nt], bb[nt], bb[nt], bb[nt]};

        // ---- x part (independent of the flag wait; hides publish latency) ----
#pragma unroll
        for (int kk = 0; kk < 8; ++kk) {
#pragma unroll
            for (int mt = 0; mt < 2; ++mt) {
                bfrag a = ld8(xb + ((long)(rb0 + mt * 16 + ct) * TT + t) * II + kk * 32 + quad * 8);
#pragma unroll
                for (int nt = 0; nt < 2; ++nt)
                    acc[mt][nt] = __builtin_amdgcn_mfma_f32_16x16x32_bf16(a, wih_f[kk][nt], acc[mt][nt], 0, 0, 0);
            }
        }

        if (t > 0) {
            // ---- wait for h(t-1) flags from all 16 WGs of this group (wave 0 polls) ----
            if (w == 0) {
                const unsigned* fp = flags + (((grp * TT + (t - 1)) << 4) | (lane & 15));
                unsigned v;
                do {
                    asm volatile("global_load_dword %0, %1, off sc0 sc1\n\ts_waitcnt vmcnt(0)"
                                 : "=v"(v) : "v"(fp) : "memory");
                } while (!__all(v != 0u));
            }
            __syncthreads();

            // ---- stage h(t-1) 32x512 bf16 -> LDS via L2-bypass (sc0 sc1) loads ----
            uint4 vv[8];
#pragma unroll
            for (int j = 0; j < 8; ++j) {
                int cid = j * 256 + tid;               // 2048 x 16B chunks
                int row = cid >> 6, c16 = cid & 63;
                const unsigned short* p = hs + ((long)(rb0 + row) * TT + (t - 1)) * HH + c16 * 8;
                asm volatile("global_load_dwordx4 %0, %1, off sc0 sc1"
                             : "=v"(vv[j]) : "v"(p));
            }
            // Drain all 8 loads. asm-volatile ordering keeps this after the loads;
            // the "memory" clobber keeps the LDS stores below from hoisting above it.
            asm volatile("s_waitcnt vmcnt(0)" ::: "memory");
#pragma unroll
            for (int j = 0; j < 8; ++j) {
                int cid = j * 256 + tid;
                int row = cid >> 6, c16 = cid & 63;
                *(uint4*)(sh + row * 520 + c16 * 8) = vv[j];
            }
            __syncthreads();

            // ---- h part: A from LDS, B from registers ----
#pragma unroll
            for (int kk = 0; kk < 16; ++kk) {
                bfrag a[2];
#pragma unroll
                for (int mt = 0; mt < 2; ++mt)
                    a[mt] = ld8(sh + (mt * 16 + ct) * 520 + kk * 32 + quad * 8);
#pragma unroll
                for (int mt = 0; mt < 2; ++mt)
#pragma unroll
                    for (int nt = 0; nt < 2; ++nt)
                        acc[mt][nt] = __builtin_amdgcn_mfma_f32_16x16x32_bf16(a[mt], whh_f[kk][nt], acc[mt][nt], 0, 0, 0);
            }
        }

        // ---- elementwise epilogue; lanes l and l^8 hold complementary gate pairs ----
#pragma unroll
        for (int mt = 0; mt < 2; ++mt) {
#pragma unroll
            for (int r = 0; r < 4; ++r) {
                float a0 = acc[mt][0][r], a1 = acc[mt][1][r];
                float b0 = __shfl_xor(a0, 8, 64);
                float b1 = __shfl_xor(a1, 8, 64);
                float iv = lo ? a0 : b0;
                float fv = lo ? b0 : a0;
                float gv = lo ? a1 : b1;
                float ov = lo ? b1 : a1;
                iv = sigm(iv); fv = sigm(fv); gv = tanh_(gv); ov = sigm(ov);
                float c = fv * cst[mt][r] + iv * gv;
                cst[mt][r] = c;
                float h = ov * tanh_(c);
                if (lo) {
                    int b = rb0 + mt * 16 + quad * 4 + r;
                    unsigned short* p = hs + ((long)b * TT + t) * HH + hcol;
                    unsigned hv = f2bf(h);
                    asm volatile("global_store_short %0, %1, off sc0 sc1"
                                 :: "v"(p), "v"(hv) : "memory");
                }
            }
        }

        // ---- publish: drain own stores (per-wave), barrier, then one flag store ----
        asm volatile("s_waitcnt vmcnt(0)" ::: "memory");
        __syncthreads();
        if (tid == 0 && t < TT - 1) {
            unsigned one = 1u;
            unsigned* p = flags + (((grp * TT + t) << 4) | wg);
            asm volatile("global_store_dword %0, %1, off sc0 sc1"
                         :: "v"(p), "v"(one) : "memory");
        }
    }
}

// ---------------- attention pooling ----------------
__global__ __launch_bounds__(256) void attn_kernel(const unsigned short* __restrict__ hs,
                                                   float* __restrict__ out) {
    int b = blockIdx.x, tid = threadIdx.x;
    int w = tid >> 6, lane = tid & 63;
    __shared__ float sc[TT];
    __shared__ float hl[HH];
    for (int c = tid; c < HH; c += 256)
        hl[c] = bf2f(hs[((long)b * TT + (TT - 1)) * HH + c]);
    __syncthreads();
    float hr[8];
#pragma unroll
    for (int j = 0; j < 8; ++j) hr[j] = hl[lane * 8 + j];
    for (int t = w; t < TT; t += 4) {                 // scores, wave-parallel over t
        u16x8 hv = *(const u16x8*)(hs + ((long)b * TT + t) * HH + lane * 8);
        float p = 0.f;
#pragma unroll
        for (int j = 0; j < 8; ++j) p += bf2f(hv[j]) * hr[j];
#pragma unroll
        for (int off = 32; off; off >>= 1) p += __shfl_xor(p, off, 64);
        if (lane == 0) sc[t] = p;
    }
    __syncthreads();
    float denom = 0.f;
    for (int t = 0; t < TT; ++t) denom += sc[t];
    float c0 = 0.f, c1 = 0.f;
    int col = tid * 2;
    for (int t = 0; t < TT; ++t) {
        float s = sc[t];
        unsigned v = *(const unsigned*)(hs + ((long)b * TT + t) * HH + col);
        c0 += s * __uint_as_float((v & 0xffffu) << 16);
        c1 += s * __uint_as_float(v & 0xffff0000u);
    }
    out[(long)b * HH + col]     = c0 / denom;
    out[(long)b * HH + col + 1] = c1 / denom;
}

extern "C" void kernel_launch(void* const* d_in, const int* in_sizes, int n_in,
                              void* d_out, int out_size, void* d_ws, size_t ws_size,
                              hipStream_t stream) {
    const float* x   = (const float*)d_in[0];
    const float* Wih = (const float*)d_in[1];
    const float* Whh = (const float*)d_in[2];
    const float* bih = (const float*)d_in[3];
    const float* bhh = (const float*)d_in[4];
    float* out = (float*)d_out;

    char* ws = (char*)d_ws;
    unsigned int*   flags = (unsigned int*)ws;                              // 256 KB
    unsigned short* hs    = (unsigned short*)(ws + 262144);                 // 134.2 MB
    unsigned short* xb    = (unsigned short*)(ws + 262144 + (size_t)BATCH * TT * HH * 2); // 67.1 MB

    (void)hipMemsetAsync(flags, 0, 262144, stream);   // poison (0xAA) -> 0; flags move 0->1 only
    cast_x_kernel<<<(BATCH * TT * II) / (256 * 8), 256, 0, stream>>>(x, xb);
    lstm_persist<<<256, 256, 0, stream>>>(Wih, Whh, bih, bhh, xb, hs, flags);
    attn_kernel<<<BATCH, 256, 0, stream>>>(hs, out);
}

// Round 4
// 1974.408 us; speedup vs baseline: 6.4839x; 1.1778x over previous
//
#include <hip/hip_runtime.h>

#define BATCH 512
#define TT    256
#define II    256
#define HH    512

typedef float f32x4  __attribute__((ext_vector_type(4)));
typedef unsigned short u16x8 __attribute__((ext_vector_type(8)));
typedef short bfrag  __attribute__((ext_vector_type(8)));   // 8 bf16 = 4 VGPRs (MFMA A/B operand)

__device__ inline unsigned short f2bf(float f) {
    unsigned u = __float_as_uint(f);
    return (unsigned short)((u + 0x7fffu + ((u >> 16) & 1u)) >> 16);   // RNE
}
__device__ inline float bf2f(unsigned short h) { return __uint_as_float(((unsigned)h) << 16); }

__device__ inline bfrag cvt8(const float* p) {   // 8 fp32 -> bf16 frag
    float4 a = *(const float4*)p;
    float4 b = *(const float4*)(p + 4);
    u16x8 u;
    u[0]=f2bf(a.x); u[1]=f2bf(a.y); u[2]=f2bf(a.z); u[3]=f2bf(a.w);
    u[4]=f2bf(b.x); u[5]=f2bf(b.y); u[6]=f2bf(b.z); u[7]=f2bf(b.w);
    return __builtin_bit_cast(bfrag, u);
}
__device__ inline bfrag ld8(const unsigned short* p) {
    return __builtin_bit_cast(bfrag, *(const u16x8*)p);
}
__device__ inline float sigm(float x) { return 1.f / (1.f + __expf(-x)); }
__device__ inline float tanh_(float x) {       // overflow-safe tanh via exp
    float ax = fabsf(x);
    float e  = __expf(-2.f * ax);
    float t  = (1.f - e) / (1.f + e);
    return copysignf(t, x);
}

// ---------------- x -> bf16 cast + transpose (B,T,I) -> (T,B,I) ----------------
// block = (b, t-chunk of 64). Reads coalesced 1KB runs, writes coalesced 512B runs.
__global__ __launch_bounds__(256) void cast_x_kernel(const float* __restrict__ x,
                                                     unsigned short* __restrict__ xt) {
    int b  = blockIdx.x >> 2;
    int t0 = (blockIdx.x & 3) * 64;
    int ic = (threadIdx.x & 31) * 8;
    int tq = threadIdx.x >> 5;          // 0..7
#pragma unroll
    for (int p = 0; p < 8; ++p) {
        int t = t0 + tq * 8 + p;
        const float* src = x + ((long)b * TT + t) * II + ic;
        float4 a = *(const float4*)src;
        float4 bb = *(const float4*)(src + 4);
        u16x8 u;
        u[0]=f2bf(a.x); u[1]=f2bf(a.y); u[2]=f2bf(a.z); u[3]=f2bf(a.w);
        u[4]=f2bf(bb.x); u[5]=f2bf(bb.y); u[6]=f2bf(bb.z); u[7]=f2bf(bb.w);
        *(u16x8*)(xt + ((long)t * BATCH + b) * II + ic) = u;
    }
}

// ---------------- persistent LSTM recurrence ----------------
// grid 256 x 256 thr. 16 groups (32 batch rows) x 16 WGs (32 h-cols each).
// Register budget fix vs R3 (which spilled ~130MB to scratch): W_ih + W_hh[k<256]
// in VGPRs (128), W_hh[k>=256] in LDS (64KB, padded rows). ~210 VGPR -> no spill.
__global__ __launch_bounds__(256, 1) void lstm_persist(
    const float* __restrict__ Wih, const float* __restrict__ Whh,
    const float* __restrict__ bih, const float* __restrict__ bhh,
    const unsigned short* __restrict__ xb,   // (T,B,I) bf16
    unsigned short* __restrict__ hs,         // (B,T,H) bf16  (ws)
    unsigned int* __restrict__ flags)        // [16 grp][256 t][16 wg], zeroed per launch
{
    const int tid  = threadIdx.x;
    const int bx   = blockIdx.x;
    const int grp  = bx >> 4;                            // batch slice
    const int wg   = bx & 15;                            // gate-col slice
    const int w    = tid >> 6;                           // wave 0..3
    const int lane = tid & 63;
    const int quad = lane >> 4;
    const int ct   = lane & 15;
    const bool lo  = (ct < 8);
    const int rb0  = grp * 32;                           // batch rows [rb0, rb0+32)
    const int hcol = wg * 32 + w * 8 + (ct & 7);

    __shared__ unsigned short sh[32 * 520];              // h(t-1) tile, rows padded 512->520
    __shared__ unsigned short wlds[128 * 264];           // Whh[:,256:512] slice, rows padded 256->264

    // W rows for this lane's two n-tiles: nt0 -> gates {i,f}, nt1 -> gates {g,o}
    int wrow[2];
    wrow[0] = ((ct >> 3) + 0) * HH + hcol;
    wrow[1] = ((ct >> 3) + 2) * HH + hcol;

    // ---- register weights: Wih (K=256) + Whh low half (K=0..255) ----
    bfrag wih_f[8][2], whh_r[8][2];
#pragma unroll
    for (int kk = 0; kk < 8; ++kk)
#pragma unroll
        for (int nt = 0; nt < 2; ++nt) {
            wih_f[kk][nt] = cvt8(Wih + (long)wrow[nt] * II + kk * 32 + quad * 8);
            whh_r[kk][nt] = cvt8(Whh + (long)wrow[nt] * HH + kk * 32 + quad * 8);
        }

    // ---- LDS weights: Whh high half (K=256..511), 128 local gate-cols x 256 ----
    for (int e = tid * 8; e < 128 * 256; e += 256 * 8) {
        int lc = e >> 8;                  // local gate-col 0..127 (= gate*32 + col-in-wg)
        int k  = e & 255;
        int row = (lc >> 5) * HH + wg * 32 + (lc & 31);
        bfrag f = cvt8(Whh + (long)row * HH + 256 + k);
        *(u16x8*)(wlds + lc * 264 + k) = __builtin_bit_cast(u16x8, f);
    }
    __syncthreads();

    // per-lane LDS offsets for B-frags (constant over steps)
    const int wl0 = ((((ct >> 3) + 0) * 32 + w * 8 + (ct & 7)) * 264) + quad * 8;
    const int wl1 = ((((ct >> 3) + 2) * 32 + w * 8 + (ct & 7)) * 264) + quad * 8;

    float bb[2];
    bb[0] = bih[wrow[0]] + bhh[wrow[0]];
    bb[1] = bih[wrow[1]] + bhh[wrow[1]];

    float cst[2][4];                                    // fp32 cell state, never rounded
#pragma unroll
    for (int mt = 0; mt < 2; ++mt)
#pragma unroll
        for (int r = 0; r < 4; ++r) cst[mt][r] = 0.f;

    for (int t = 0; t < TT; ++t) {
        f32x4 acc[2][2];
#pragma unroll
        for (int mt = 0; mt < 2; ++mt)
#pragma unroll
            for (int nt = 0; nt < 2; ++nt)
                acc[mt][nt] = (f32x4){bb[nt], bb[nt], bb[nt], bb[nt]};

        // ---- x part: (T,B,I) layout -> fully coalesced; hides publish latency ----
#pragma unroll
        for (int kk = 0; kk < 8; ++kk) {
#pragma unroll
            for (int mt = 0; mt < 2; ++mt) {
                bfrag a = ld8(xb + ((long)t * BATCH + rb0 + mt * 16 + ct) * II + kk * 32 + quad * 8);
#pragma unroll
                for (int nt = 0; nt < 2; ++nt)
                    acc[mt][nt] = __builtin_amdgcn_mfma_f32_16x16x32_bf16(a, wih_f[kk][nt], acc[mt][nt], 0, 0, 0);
            }
        }

        if (t > 0) {
            // ---- wait for h(t-1) flags from all 16 WGs of this group (wave 0 polls) ----
            if (w == 0) {
                const unsigned* fp = flags + (((grp * TT + (t - 1)) << 4) | (lane & 15));
                unsigned v;
                do {
                    asm volatile("global_load_dword %0, %1, off sc0 sc1\n\ts_waitcnt vmcnt(0)"
                                 : "=v"(v) : "v"(fp) : "memory");
                } while (!__all(v != 0u));
            }
            __syncthreads();

            // ---- stage h(t-1) 32x512 bf16 -> LDS via L2-bypass (sc0 sc1) loads ----
            uint4 vv[8];
#pragma unroll
            for (int j = 0; j < 8; ++j) {
                int cid = j * 256 + tid;               // 2048 x 16B chunks
                int row = cid >> 6, c16 = cid & 63;
                const unsigned short* p = hs + ((long)(rb0 + row) * TT + (t - 1)) * HH + c16 * 8;
                asm volatile("global_load_dwordx4 %0, %1, off sc0 sc1"
                             : "=v"(vv[j]) : "v"(p));
            }
            asm volatile("s_waitcnt vmcnt(0)" ::: "memory");
#pragma unroll
            for (int j = 0; j < 8; ++j) {
                int cid = j * 256 + tid;
                int row = cid >> 6, c16 = cid & 63;
                *(uint4*)(sh + row * 520 + c16 * 8) = vv[j];
            }
            __syncthreads();

            // ---- h part, K=0..255: B from registers ----
#pragma unroll
            for (int kk = 0; kk < 8; ++kk) {
                bfrag a[2];
#pragma unroll
                for (int mt = 0; mt < 2; ++mt)
                    a[mt] = ld8(sh + (mt * 16 + ct) * 520 + kk * 32 + quad * 8);
#pragma unroll
                for (int mt = 0; mt < 2; ++mt)
#pragma unroll
                    for (int nt = 0; nt < 2; ++nt)
                        acc[mt][nt] = __builtin_amdgcn_mfma_f32_16x16x32_bf16(a[mt], whh_r[kk][nt], acc[mt][nt], 0, 0, 0);
            }
            // ---- h part, K=256..511: B from LDS ----
#pragma unroll
            for (int kk = 0; kk < 8; ++kk) {
                bfrag a[2], b[2];
#pragma unroll
                for (int mt = 0; mt < 2; ++mt)
                    a[mt] = ld8(sh + (mt * 16 + ct) * 520 + (8 + kk) * 32 + quad * 8);
                b[0] = ld8(wlds + wl0 + kk * 32);
                b[1] = ld8(wlds + wl1 + kk * 32);
#pragma unroll
                for (int mt = 0; mt < 2; ++mt)
#pragma unroll
                    for (int nt = 0; nt < 2; ++nt)
                        acc[mt][nt] = __builtin_amdgcn_mfma_f32_16x16x32_bf16(a[mt], b[nt], acc[mt][nt], 0, 0, 0);
            }
        }

        // ---- elementwise epilogue; lanes l and l^8 hold complementary gate pairs ----
#pragma unroll
        for (int mt = 0; mt < 2; ++mt) {
#pragma unroll
            for (int r = 0; r < 4; ++r) {
                float a0 = acc[mt][0][r], a1 = acc[mt][1][r];
                float b0 = __shfl_xor(a0, 8, 64);
                float b1 = __shfl_xor(a1, 8, 64);
                float iv = lo ? a0 : b0;
                float fv = lo ? b0 : a0;
                float gv = lo ? a1 : b1;
                float ov = lo ? b1 : a1;
                iv = sigm(iv); fv = sigm(fv); gv = tanh_(gv); ov = sigm(ov);
                float c = fv * cst[mt][r] + iv * gv;
                cst[mt][r] = c;
                float h = ov * tanh_(c);
                if (lo) {
                    int b = rb0 + mt * 16 + quad * 4 + r;
                    unsigned short* p = hs + ((long)b * TT + t) * HH + hcol;
                    unsigned hv = f2bf(h);
                    asm volatile("global_store_short %0, %1, off sc0 sc1"
                                 :: "v"(p), "v"(hv) : "memory");
                }
            }
        }

        // ---- publish: drain own stores, barrier, then one flag store ----
        asm volatile("s_waitcnt vmcnt(0)" ::: "memory");
        __syncthreads();
        if (tid == 0 && t < TT - 1) {
            unsigned one = 1u;
            unsigned* p = flags + (((grp * TT + t) << 4) | wg);
            asm volatile("global_store_dword %0, %1, off sc0 sc1"
                         :: "v"(p), "v"(one) : "memory");
        }
    }
}

// ---------------- attention pooling ----------------
__global__ __launch_bounds__(256) void attn_kernel(const unsigned short* __restrict__ hs,
                                                   float* __restrict__ out) {
    int b = blockIdx.x, tid = threadIdx.x;
    int w = tid >> 6, lane = tid & 63;
    __shared__ float sc[TT];
    __shared__ float hl[HH];
    for (int c = tid; c < HH; c += 256)
        hl[c] = bf2f(hs[((long)b * TT + (TT - 1)) * HH + c]);
    __syncthreads();
    float hr[8];
#pragma unroll
    for (int j = 0; j < 8; ++j) hr[j] = hl[lane * 8 + j];
    for (int t = w; t < TT; t += 4) {                 // scores, wave-parallel over t
        u16x8 hv = *(const u16x8*)(hs + ((long)b * TT + t) * HH + lane * 8);
        float p = 0.f;
#pragma unroll
        for (int j = 0; j < 8; ++j) p += bf2f(hv[j]) * hr[j];
#pragma unroll
        for (int off = 32; off; off >>= 1) p += __shfl_xor(p, off, 64);
        if (lane == 0) sc[t] = p;
    }
    __syncthreads();
    float denom = 0.f;
    for (int t = 0; t < TT; ++t) denom += sc[t];
    float c0 = 0.f, c1 = 0.f;
    int col = tid * 2;
    for (int t = 0; t < TT; ++t) {
        float s = sc[t];
        unsigned v = *(const unsigned*)(hs + ((long)b * TT + t) * HH + col);
        c0 += s * __uint_as_float((v & 0xffffu) << 16);
        c1 += s * __uint_as_float(v & 0xffff0000u);
    }
    out[(long)b * HH + col]     = c0 / denom;
    out[(long)b * HH + col + 1] = c1 / denom;
}

extern "C" void kernel_launch(void* const* d_in, const int* in_sizes, int n_in,
                              void* d_out, int out_size, void* d_ws, size_t ws_size,
                              hipStream_t stream) {
    const float* x   = (const float*)d_in[0];
    const float* Wih = (const float*)d_in[1];
    const float* Whh = (const float*)d_in[2];
    const float* bih = (const float*)d_in[3];
    const float* bhh = (const float*)d_in[4];
    float* out = (float*)d_out;

    char* ws = (char*)d_ws;
    unsigned int*   flags = (unsigned int*)ws;                              // 256 KB
    unsigned short* hs    = (unsigned short*)(ws + 262144);                 // 134.2 MB
    unsigned short* xb    = (unsigned short*)(ws + 262144 + (size_t)BATCH * TT * HH * 2); // 67.1 MB

    (void)hipMemsetAsync(flags, 0, 262144, stream);   // poison (0xAA) -> 0; flags move 0->1 only
    cast_x_kernel<<<BATCH * (TT / 64), 256, 0, stream>>>(x, xb);
    lstm_persist<<<256, 256, 0, stream>>>(Wih, Whh, bih, bhh, xb, hs, flags);
    attn_kernel<<<BATCH, 256, 0, stream>>>(hs, out);
}